// Round 1
// baseline (818.043 us; speedup 1.0000x reference)
//
#include <hip/hip_runtime.h>
#include <math.h>

// DecoderCategorical: probs = [exp(beta[:-1]@z), 1] / (1+sum) -> one-hot(argmax)
// Z: (T, 64) fp32, beta: (32, 64) fp32 (row 31 unused), out: (T, 32) fp32 one-hot.
// v3: coalesced reads via wave-local LDS transpose.
//   v2 read Z with lanes at 256 B stride -> every global_load_dwordx4 touched 64
//   distinct cache lines with 16 B used each: 8x request inflation, measured ~6x
//   off the 122 us memory roofline. v3 loads each 64-row tile with lane-contiguous
//   dwordx4 (8 full 128 B lines per instruction), bounces through XOR-swizzled LDS
//   (bank-conflict-free b128 on both sides), and reads rows back in the EXACT
//   sequential d-order of v2 -> bitwise-identical logits/exp/div/argmax.
//   Wave-local only: no __syncthreads (no vmcnt-drain), wave_barrier is free.
//   Half-1 globals issue before half-0 compute so HBM latency hides under fmacs.

constexpr int DZ = 64;
constexpr int DC = 32;
constexpr int NC = 31;          // active categories (beta[:-1])
constexpr int BLOCK = 256;
constexpr int WAVES = BLOCK / 64;

__global__ __launch_bounds__(BLOCK) void decoder_cat_kernel(
    const float* __restrict__ Z, const float* __restrict__ beta,
    float* __restrict__ out, int T)
{
    const int tid  = threadIdx.x;
    const int lane = tid & 63;
    const int wave = tid >> 6;
    const int wrow0 = blockIdx.x * BLOCK + (tid & ~63);  // first row of wave's 64-row tile

    // 8 KB per wave (one 32-float half of 64 rows), reused for both halves.
    __shared__ float lds[WAVES][2048];
    float* __restrict__ wl = lds[wave];

    // Staging geometry: global chunk n = j*64 + lane covers rows 8 at a time,
    // lane = subrow*8 + sc -> addr (wrow0+subrow+8j)*256B + sc*16B : per
    // instruction 64 lanes cover 8 complete aligned 128B lines. LDS slot
    // p = n ^ ((n>>3)&7): low-3 XOR spreads the read-side row stride (128 B)
    // across all banks; both ds_write_b128 and ds_read_b128 run at the
    // conflict-free minimum.
    const int subrow = lane >> 3;          // 0..7
    const int sc     = lane & 7;           // 16B chunk within half-row
    const int wbase  = subrow * 32 + ((sc ^ subrow) * 4);  // write float offset (+ j*256)
    float* const rb  = wl + lane * 32;     // this lane's (swizzled) row base

    const bool full = (wrow0 + 64) <= T;   // wave-uniform

    float acc[NC];
#pragma unroll
    for (int c = 0; c < NC; ++c) acc[c] = 0.0f;

    const float* gb = Z + (size_t)(wrow0 + subrow) * DZ + sc * 4;

    // ---- stage half 0 (d = 0..31), coalesced ----
    float4 g0[8];
    if (full) {
#pragma unroll
        for (int j = 0; j < 8; ++j) g0[j] = *(const float4*)(gb + j * (8 * DZ));
    } else {
#pragma unroll
        for (int j = 0; j < 8; ++j) {
            int r = wrow0 + subrow + 8 * j; r = (r < T) ? r : (T - 1);
            g0[j] = *(const float4*)(Z + (size_t)r * DZ + sc * 4);
        }
    }
#pragma unroll
    for (int j = 0; j < 8; ++j) *(float4*)(wl + j * 256 + wbase) = g0[j];

    // ---- issue half-1 globals now; they fly during half-0 compute ----
    float4 g1[8];
    if (full) {
#pragma unroll
        for (int j = 0; j < 8; ++j) g1[j] = *(const float4*)(gb + 32 + j * (8 * DZ));
    } else {
#pragma unroll
        for (int j = 0; j < 8; ++j) {
            int r = wrow0 + subrow + 8 * j; r = (r < T) ? r : (T - 1);
            g1[j] = *(const float4*)(Z + (size_t)r * DZ + 32 + sc * 4);
        }
    }
    __builtin_amdgcn_wave_barrier();   // writes above ordered before reads below

    // Per-chunk consume: beta index is thread-uniform (s_load path, SGPR operand
    // in v_fmac). Sequential-d fmaf order per category matches v2 exactly.
    auto consume_half = [&](int hbase) {
#pragma unroll
        for (int c = 0; c < 8; ++c) {
            const float4 z4 = *(const float4*)(rb + ((c ^ sc) * 4));
            const int d4 = hbase + c;
#pragma unroll
            for (int cat = 0; cat < NC; ++cat) {
                const float* b = beta + cat * DZ + d4 * 4;
                acc[cat] = fmaf(b[3], z4.w,
                           fmaf(b[2], z4.z,
                           fmaf(b[1], z4.y,
                           fmaf(b[0], z4.x, acc[cat]))));
            }
        }
    };

    consume_half(0);
    __builtin_amdgcn_wave_barrier();   // half-0 reads ordered before half-1 writes

    // ---- stage half 1 (d = 32..63) into the same buffer ----
#pragma unroll
    for (int j = 0; j < 8; ++j) *(float4*)(wl + j * 256 + wbase) = g1[j];
    __builtin_amdgcn_wave_barrier();

    consume_half(8);

    // e = exp(logits) once (explicit CSE); norm = 1 + sum(e).
    float s = 1.0f;
#pragma unroll
    for (int c = 0; c < NC; ++c) { acc[c] = expf(acc[c]); s += acc[c]; }

    // probs = [e/norm, 1/norm], first-max-wins argmax. IEEE divides to match
    // the numpy reference's rounding exactly (monotone but tie-creating; the
    // divide must be real to reproduce ref's ties).
    float best = -1.0f;
    int   bidx = 0;
#pragma unroll
    for (int c = 0; c < NC; ++c) {
        float p = acc[c] / s;
        if (p > best) { best = p; bidx = c; }
    }
    if (1.0f / s > best) bidx = NC;

    // Coalesced one-hot stores: redistribute argmax indices across the wave
    // so each store inst writes 1 KB contiguous (64 lanes x float4).
#pragma unroll
    for (int k = 0; k < 8; ++k) {
        int cid = lane + 64 * k;            // 64 rows x 8 float4 chunks
        int r   = cid >> 3;
        int c4  = cid & 7;
        int widx = __shfl(bidx, r, 64);
        int grow = wrow0 + r;
        if (grow < T) {
            float4 v;
            v.x = (c4 * 4 + 0 == widx) ? 1.0f : 0.0f;
            v.y = (c4 * 4 + 1 == widx) ? 1.0f : 0.0f;
            v.z = (c4 * 4 + 2 == widx) ? 1.0f : 0.0f;
            v.w = (c4 * 4 + 3 == widx) ? 1.0f : 0.0f;
            *(float4*)(out + (size_t)grow * DC + c4 * 4) = v;
        }
    }
}

extern "C" void kernel_launch(void* const* d_in, const int* in_sizes, int n_in,
                              void* d_out, int out_size, void* d_ws, size_t ws_size,
                              hipStream_t stream)
{
    const float* Z    = (const float*)d_in[0];
    const float* beta = (const float*)d_in[1];
    float* out        = (float*)d_out;
    const int T = in_sizes[0] / DZ;           // 2,000,000
    const int grid = (T + BLOCK - 1) / BLOCK; // 7813
    hipLaunchKernelGGL(decoder_cat_kernel, dim3(grid), dim3(BLOCK), 0, stream,
                       Z, beta, out, T);
}